// Round 9
// baseline (115.299 us; speedup 1.0000x reference)
//
#include <hip/hip_runtime.h>

// out[b][t][w] (f32x4) = x[b][(t + w - 15) mod T] (f32x4)
// B=128, T=16384, F=4, wow=16.
//
// R8 structure with CACHED stores (the one untested store-path variable):
// 8192 resident waves, each owning one contiguous 64 KB output region
// (16 iterations x 4 KB). Regular stores aggregate in L2/L3 and write back
// in large sorted batches — the same path the 6.7 TB/s fill kernel uses.
// Loads deduped via __shfl (lanes 0..30 hold the 31 needed x rows).

typedef float f32x4 __attribute__((ext_vector_type(4)));

__global__ __launch_bounds__(256, 8) void ring_pad_kernel(
    const f32x4* __restrict__ x, f32x4* __restrict__ out) {
    constexpr int T    = 16384;
    constexpr int ITER = 16;

    int lane = threadIdx.x & 63;
    int g    = (((int)blockIdx.x << 8) + threadIdx.x) >> 6;  // wave id 0..8191

    int w  = lane & 15;              // window slot
    int tl = (lane >> 4) & 3;        // row-within-quad
    int j  = lane < 31 ? lane : 30;  // source-row slot held by this lane

    #pragma unroll 2
    for (int m = 0; m < ITER; ++m) {
        int c  = g * ITER + m;       // 16-row chunk id: wave-sequential
        int b  = c >> 10;            // batch
        int R0 = (c & 1023) << 4;    // first output t-row of chunk

        // lane j holds x[b, (R0 - 15 + j) mod T]
        f32x4 r = x[((size_t)b << 14) + ((R0 - 15 + j) & (T - 1))];

        f32x4* ob = out + ((size_t)c << 8);
        #pragma unroll
        for (int s = 0; s < 4; ++s) {
            int src = s * 4 + tl + w;          // 0..30
            f32x4 v;
            v[0] = __shfl(r[0], src, 64);
            v[1] = __shfl(r[1], src, 64);
            v[2] = __shfl(r[2], src, 64);
            v[3] = __shfl(r[3], src, 64);
            ob[s * 64 + lane] = v;             // cached store (L2/L3 writeback)
        }
    }
}

extern "C" void kernel_launch(void* const* d_in, const int* in_sizes, int n_in,
                              void* d_out, int out_size, void* d_ws, size_t ws_size,
                              hipStream_t stream) {
    const f32x4* x = (const f32x4*)d_in[0];   // (128, 16384, 4) fp32
    f32x4* out = (f32x4*)d_out;               // (128, 16384, 64) fp32

    ring_pad_kernel<<<2048, 256, 0, stream>>>(x, out);
}